// Round 10
// baseline (479.080 us; speedup 1.0000x reference)
//
#include <hip/hip_runtime.h>
#include <hip/hip_bf16.h>

#define BS_   2048
#define HID_  512
#define PH_   32
#define GRP_  16        // blocks per sync group

// s_getreg: size=4 bits (sz-1=3), offset=0, id=20 (HW_REG_XCC_ID, m09-verified)
#define HWREG_XCC_ID ((3 << 11) | (0 << 6) | 20)

typedef _Float16 half8 __attribute__((ext_vector_type(8)));
typedef float floatx4 __attribute__((ext_vector_type(4)));

__device__ __forceinline__ float sigf(float x) { return 1.f / (1.f + __expf(-x)); }
__device__ __forceinline__ float tanhfast(float x) {
    float e = __expf(2.f * x);          // e=inf -> 1, e->0 -> -1 : safe at extremes
    return 1.f - 2.f / (e + 1.f);
}

// ---------------------------------------------------------------------------
// Prep: fp16 weights (W_ih, W_ih+W_hh), combined bias, z16, zero step
// counters (512) + per-group XCD masks (8) = 520 ints.
// ---------------------------------------------------------------------------
__global__ __launch_bounds__(256) void prep_kernel(
    const float* __restrict__ Wih, const float* __restrict__ Whh,
    const float* __restrict__ bih, const float* __restrict__ bhh,
    const float* __restrict__ z,
    _Float16* __restrict__ wih16, _Float16* __restrict__ wsum16,
    _Float16* __restrict__ z16, float* __restrict__ bsum,
    int* __restrict__ cnt)
{
    int i = blockIdx.x * 256 + threadIdx.x;          // [0, 1048576)
    if (i < BS_ * HID_) z16[i] = (_Float16)z[i];
    if (i < 4 * HID_ * HID_) {
        float a = Wih[i];
        wih16[i]  = (_Float16)a;
        wsum16[i] = (_Float16)(a + Whh[i]);
    }
    if (i < 4 * HID_) bsum[i] = bih[i] + bhh[i];
    if (i < 520) cnt[i] = 0;
}

// ---------------------------------------------------------------------------
// Stage a 32-hid weight slice: 128 gate rows x 512 K fp16 = 128 KB LDS,
// XOR-swizzled on 16B blocks.
// ---------------------------------------------------------------------------
__device__ __forceinline__ void stage_weights(_Float16* Wl, const _Float16* Wg,
                                              int j, int tid)
{
#pragma unroll
    for (int rep = 0; rep < 16; ++rep) {
        int idx = rep * 512 + tid;      // [0, 8192): row n in [0,128), kb in [0,64)
        int n  = idx >> 6;
        int kb = idx & 63;
        int g  = n >> 5, u = n & 31;    // gate, hid-within-slice
        const half8* src = (const half8*)(Wg + ((size_t)(g * HID_ + j * 32 + u)) * HID_ + kb * 8);
        int phys = (kb & 56) | ((kb & 7) ^ (n & 7));
        *(half8*)((char*)Wl + n * 1024 + phys * 16) = *src;
    }
}

// ---------------------------------------------------------------------------
// Persistent LSTM (R9 chassis) + fused dense partials + runtime-gated
// XCD-local L2 hand-off.
//
// Grid = 256 x 512. ib = blockIdx & 15 (128-row batch tile), j = blockIdx>>4
// (32 hid units = 128 gate rows, 128 KB LDS, restaged once at the t=0 tail).
// Wave wv: M-strip (wv&3)*32 rows, hid-half wv>>2.
//
// Hand-off:
//   t=0: WT stores (CP) unconditionally; tid0 ORs its physical XCD bit into
//        the group mask, then signals with a RELEASE RMW (orders OR < signal
//        at the CP -- this ordering hole may have silently disabled R4/R5).
//   t=1 wait guarantees the mask is complete; popcount==1 -> all 16 blocks
//        share one physical L2 -> FAST: plain write-back stores, relaxed
//        CP-RMW signal/poll, zero cache-ops. Consumer loads are to fresh
//        addresses every step (each t-plane read once), so no stale L1/L2
//        copies exist; the dirty L2 lines serve them directly.
//   popcount>1 -> R9's WT path (placement-independent, proven).
// Per-wave sync regressed 4-5x (R7/R8 poll storms) -- do not re-attempt.
//
// Dense fusion: per h value, partial y = h*Wd reduced over the 16-lane hid
// nibble via shfl_xor, stored contention-free to yp[t][slice32][row][2].
// ---------------------------------------------------------------------------
__global__ __launch_bounds__(512) void lstm_persist(
    const _Float16* __restrict__ wih16, const _Float16* __restrict__ wsum16,
    const float* __restrict__ bsum, const _Float16* __restrict__ z16,
    _Float16* __restrict__ hs, int* __restrict__ cnt,
    const float* __restrict__ Wd, float* __restrict__ yp)
{
    __shared__ _Float16 Wl[128 * 512];   // 128 KB
    __shared__ int sh_fast;

    const int tid  = threadIdx.x;
    const int ib   = blockIdx.x & 15;
    const int j    = blockIdx.x >> 4;
    const int lane = tid & 63;
    const int wv   = tid >> 6;
    const int ms   = wv & 3;            // M-strip: 32 rows of the 128-row tile
    const int hh   = wv >> 2;           // hid half: 0 -> units 0..15, 1 -> 16..31
    const int qw   = lane >> 4;         // quad 0..3
    const int ln   = lane & 15;
    const int hid  = j * 32 + hh * 16 + ln;

    stage_weights(Wl, wih16, j, tid);

    float bias[4];
#pragma unroll
    for (int g = 0; g < 4; ++g) bias[g] = bsum[g * HID_ + hid];
    const float wd0 = Wd[hid];
    const float wd1 = Wd[HID_ + hid];

    float c[2][4];
#pragma unroll
    for (int mt = 0; mt < 2; ++mt)
#pragma unroll
        for (int r = 0; r < 4; ++r) c[mt][r] = 0.f;

    const char* Bl = (const char*)Wl;
    const int tE = (qw ^ (ln & 7)) * 16;    // swizzled byte offset, kk-even
    const int rowB = hh * 16 + ln;          // LDS row within a gate's 32 rows

    bool fast = false;
    int* xmask = cnt + 512;

    __syncthreads();

    for (int t = 0; t < PH_; ++t) {
        const _Float16* xx = (t == 0) ? z16 : hs + (size_t)(t - 1) * BS_ * HID_;

        if (t >= 1) {
            if (tid == 0) {
                while (__hip_atomic_fetch_add(&cnt[ib * 32 + t - 1], 0,
                                              __ATOMIC_RELAXED,
                                              __HIP_MEMORY_SCOPE_AGENT) < GRP_) {
                    __builtin_amdgcn_s_sleep(1);
                }
                if (t == 1) {
                    int m = __hip_atomic_fetch_add(&xmask[ib], 0,
                                                   __ATOMIC_RELAXED,
                                                   __HIP_MEMORY_SCOPE_AGENT);
                    sh_fast = (__popc((unsigned)m) == 1) ? 1 : 0;
                }
            }
            __syncthreads();    // orders all following loads after the poll
            if (t == 1) fast = (sh_fast != 0);
        }

        floatx4 acc[2][4];                  // bias pre-folded
#pragma unroll
        for (int mt = 0; mt < 2; ++mt)
#pragma unroll
            for (int g = 0; g < 4; ++g)
                acc[mt][g] = (floatx4){bias[g], bias[g], bias[g], bias[g]};

        // A fragment: A[m = ln][k = qw*8 + jj]; depth-4 global prefetch ring
        const _Float16* A0 = xx + (size_t)(ib * 128 + ms * 32 + ln) * HID_ + qw * 8;

        half8 a0r[4], a1r[4], bA[4], bB[4];
#pragma unroll
        for (int p = 0; p < 4; ++p) {
            a0r[p] = *(const half8*)(A0 + p * 32);
            a1r[p] = *(const half8*)(A0 + 16 * HID_ + p * 32);
        }
#pragma unroll
        for (int g = 0; g < 4; ++g)
            bA[g] = *(const half8*)(Bl + (g * 32 + rowB) * 1024 + tE);

#pragma unroll
        for (int kk = 0; kk < 16; ++kk) {
            half8 ca0 = a0r[kk & 3], ca1 = a1r[kk & 3];
            if (kk < 12) {
                a0r[kk & 3] = *(const half8*)(A0 + (kk + 4) * 32);
                a1r[kk & 3] = *(const half8*)(A0 + 16 * HID_ + (kk + 4) * 32);
            }
            half8* cb = (kk & 1) ? bB : bA;
            half8* nb = (kk & 1) ? bA : bB;
            if (kk < 15) {
                int k1 = kk + 1;
#pragma unroll
                for (int g = 0; g < 4; ++g) {
                    int off = (g * 32 + rowB) * 1024 + (k1 >> 1) * 128 + (tE ^ ((k1 & 1) << 6));
                    nb[g] = *(const half8*)(Bl + off);
                }
            }
#pragma unroll
            for (int g = 0; g < 4; ++g) {
                acc[0][g] = __builtin_amdgcn_mfma_f32_16x16x32_f16(ca0, cb[g], acc[0][g], 0, 0, 0);
                acc[1][g] = __builtin_amdgcn_mfma_f32_16x16x32_f16(ca1, cb[g], acc[1][g], 0, 0, 0);
            }
        }

        // epilogue: C/D layout col=ln, row=qw*4+r; all 4 gates in-thread.
        _Float16* hb = hs + (size_t)t * BS_ * HID_
                          + (size_t)(ib * 128 + ms * 32 + qw * 4) * HID_ + hid;
        float* ypb = yp + ((size_t)(t * 32 + (j * 2 + hh)) * 2048) * 2;
#pragma unroll
        for (int mt = 0; mt < 2; ++mt) {
#pragma unroll
            for (int r = 0; r < 4; ++r) {
                float gi = acc[mt][0][r];
                float gf = acc[mt][1][r];
                float gg = acc[mt][2][r];
                float go = acc[mt][3][r];
                float cn = sigf(gf) * c[mt][r] + sigf(gi) * tanhfast(gg);
                float hn = sigf(go) * tanhfast(cn);
                c[mt][r] = cn;

                // fused dense partial: reduce h*wd over the 16-lane hid nibble
                float p0 = hn * wd0, p1 = hn * wd1;
#pragma unroll
                for (int m = 1; m <= 8; m <<= 1) {
                    p0 += __shfl_xor(p0, m);
                    p1 += __shfl_xor(p1, m);
                }
                if (ln == 0) {
                    int row = ib * 128 + ms * 32 + mt * 16 + qw * 4 + r;
                    *(float2*)(ypb + (size_t)row * 2) = make_float2(p0, p1);
                }

                if (t < PH_ - 1) {      // h[31] is never consumed
                    if (fast) {
                        hb[(size_t)(mt * 16 + r) * HID_] = (_Float16)hn;
                    } else {
                        _Float16 hf = (_Float16)hn;
                        short hv;
                        __builtin_memcpy(&hv, &hf, 2);
                        __hip_atomic_store((short*)(hb + (size_t)(mt * 16 + r) * HID_), hv,
                                           __ATOMIC_RELAXED, __HIP_MEMORY_SCOPE_AGENT);
                    }
                }
            }
        }

        // Barrier drains every wave's stores (vmcnt(0): L2-acked in fast mode,
        // CP-acked for WT), then ONE CP-RMW signals the group.
        __syncthreads();
        if (t == 0) {
            if (tid == 0) {
                int xcd = __builtin_amdgcn_s_getreg(HWREG_XCC_ID) & 0xf;
                __hip_atomic_fetch_or(&xmask[ib], 1 << xcd,
                                      __ATOMIC_RELAXED, __HIP_MEMORY_SCOPE_AGENT);
                // RELEASE: mask-OR ordered before the signal at the CP
                __hip_atomic_fetch_add(&cnt[ib * 32], 1,
                                       __ATOMIC_RELEASE, __HIP_MEMORY_SCOPE_AGENT);
            }
            stage_weights(Wl, wsum16, j, tid);   // switch to W_ih+W_hh (once)
            __syncthreads();
        } else if (t < PH_ - 1) {
            if (tid == 0)
                __hip_atomic_fetch_add(&cnt[ib * 32 + t], 1,
                                       __ATOMIC_RELAXED, __HIP_MEMORY_SCOPE_AGENT);
        }
    }
}

// ---------------------------------------------------------------------------
// y[b,t,:] = bd + sum over 32 slices of yp[t][s][b][:]. One thread per (t,b).
// ---------------------------------------------------------------------------
__global__ __launch_bounds__(256) void reduce_kernel(
    const float* __restrict__ yp, const float* __restrict__ bd,
    float* __restrict__ y)
{
    int gw = blockIdx.x * 256 + threadIdx.x;    // [0, 65536)
    int b = gw & 2047, t = gw >> 11;
    float s0 = bd[0], s1 = bd[1];
#pragma unroll 4
    for (int s = 0; s < 32; ++s) {
        float2 v = *(const float2*)(yp + ((size_t)(t * 32 + s) * 2048 + b) * 2);
        s0 += v.x; s1 += v.y;
    }
    float* o = y + ((size_t)b * PH_ + t) * 2;
    o[0] = s0; o[1] = s1;
}

// ---------------------------------------------------------------------------
extern "C" void kernel_launch(void* const* d_in, const int* in_sizes, int n_in,
                              void* d_out, int out_size, void* d_ws, size_t ws_size,
                              hipStream_t stream)
{
    (void)in_sizes; (void)n_in; (void)out_size; (void)ws_size;
    // setup_inputs order: hist(0, unused), z(1), W_ih(2), W_hh(3), b_ih(4),
    //                     b_hh(5), W_d(6), b_d(7)
    const float* z   = (const float*)d_in[1];
    const float* Wih = (const float*)d_in[2];
    const float* Whh = (const float*)d_in[3];
    const float* bih = (const float*)d_in[4];
    const float* bhh = (const float*)d_in[5];
    const float* Wd  = (const float*)d_in[6];
    const float* bd  = (const float*)d_in[7];
    float* y = (float*)d_out;

    char* ws = (char*)d_ws;
    _Float16* hs     = (_Float16*)ws;                          // 64 MB
    _Float16* z16    = (_Float16*)(ws + (size_t)67108864);     // 2 MB
    _Float16* wih16  = (_Float16*)(ws + (size_t)69206016);     // 2 MB
    _Float16* wsum16 = (_Float16*)(ws + (size_t)71303168);     // 2 MB
    float*    bsum   = (float*)   (ws + (size_t)73400320);     // 8 KB
    int*      cnt    = (int*)     (ws + (size_t)73408512);     // 520 ints
    float*    yp     = (float*)   (ws + (size_t)73412608);     // 16 MB

    prep_kernel<<<4096, 256, 0, stream>>>(Wih, Whh, bih, bhh, z,
                                          wih16, wsum16, z16, bsum, cnt);

    {
        const void* k = (const void*)lstm_persist;
        void* args[] = {(void*)&wih16, (void*)&wsum16, (void*)&bsum,
                        (void*)&z16, (void*)&hs, (void*)&cnt,
                        (void*)&Wd, (void*)&yp};
        hipLaunchCooperativeKernel(k, dim3(256), dim3(512), args, 0, stream);
    }

    reduce_kernel<<<256, 256, 0, stream>>>(yp, bd, y);
}